// Round 1
// baseline (953.334 us; speedup 1.0000x reference)
//
#include <hip/hip_runtime.h>
#include <hip/hip_bf16.h>
#include <cstdint>

typedef unsigned short u16;
typedef __bf16 v8bf __attribute__((ext_vector_type(8)));
typedef float v4f __attribute__((ext_vector_type(4)));

__device__ __forceinline__ u16 f2bf(float f) {
  union { float f; uint32_t u; } v; v.f = f;
  return (u16)((v.u + 0x7fffu + ((v.u >> 16) & 1u)) >> 16);
}

// async global->LDS, 16B per lane; LDS dest = wave-uniform base + lane*16
#define GLL16(gsrc, ldst) \
  __builtin_amdgcn_global_load_lds((__attribute__((address_space(1))) void*)(gsrc), \
      (__attribute__((address_space(3))) void*)(ldst), 16, 0, 0)

// ---------------- LayerNorm: fp32 row -> bf16 row ----------------
__global__ __launch_bounds__(256) void ln_kernel(
    const float* __restrict__ x, const float* __restrict__ g, const float* __restrict__ bt,
    u16* __restrict__ out)
{
  int row = blockIdx.x, tid = threadIdx.x;
  const float4* xr = (const float4*)(x + (size_t)row * 1024);
  float4 v = xr[tid];
  float s = v.x + v.y + v.z + v.w;
  float ss = v.x*v.x + v.y*v.y + v.z*v.z + v.w*v.w;
  for (int d = 1; d < 64; d <<= 1) { s += __shfl_xor(s, d); ss += __shfl_xor(ss, d); }
  __shared__ float red[8];
  int wv = tid >> 6, lane = tid & 63;
  if (lane == 0) { red[wv] = s; red[4 + wv] = ss; }
  __syncthreads();
  s  = red[0] + red[1] + red[2] + red[3];
  ss = red[4] + red[5] + red[6] + red[7];
  float mean = s * (1.f/1024.f);
  float var  = ss * (1.f/1024.f) - mean*mean;      // biased var == jnp.var
  float rs = rsqrtf(var + 1e-5f);
  float4 gv = ((const float4*)g)[tid];
  float4 bv = ((const float4*)bt)[tid];
  ushort4 o;
  o.x = f2bf((v.x-mean)*rs*gv.x + bv.x);
  o.y = f2bf((v.y-mean)*rs*gv.y + bv.y);
  o.z = f2bf((v.z-mean)*rs*gv.z + bv.z);
  o.w = f2bf((v.w-mean)*rs*gv.w + bv.w);
  ((ushort4*)out)[(size_t)row*256 + tid] = o;
}

// ------------- Weight transpose + fp32->bf16 cast: W[K][N] -> WT[N][K] -------------
__global__ __launch_bounds__(256) void transpose_cast(
    const float* __restrict__ W, u16* __restrict__ WT, int K, int N)
{
  __shared__ float t[32][33];
  int tiles_n = N >> 5;
  int bn = blockIdx.x % tiles_n, bk = blockIdx.x / tiles_n;
  int tx = threadIdx.x & 31, ty = threadIdx.x >> 5;   // 32 x 8
  #pragma unroll
  for (int j = 0; j < 4; ++j)
    t[ty + j*8][tx] = W[(size_t)(bk*32 + ty + j*8) * N + bn*32 + tx];
  __syncthreads();
  #pragma unroll
  for (int j = 0; j < 4; ++j)
    WT[(size_t)(bn*32 + ty + j*8) * K + bk*32 + tx] = f2bf(t[tx][ty + j*8]);
}

// ---------------- GEMM: C[M,N] = A[M,K](bf16) * Wt[N,K](bf16)^T, templated epilogue ----------------
// EPI: 0 = bf16 out; 1 = bias+GELU(exact) bf16 out; 2 = bias fp32 out;
//      3 = bias + r1 + r2 fp32 out; 4 = bias + r1 fp32 out
template<int EPI>
__global__ __launch_bounds__(256, 2) void gemm_bf16(
    const u16* __restrict__ A, const u16* __restrict__ Bt, void* __restrict__ Cout,
    const float* __restrict__ bias, const float* __restrict__ r1, const float* __restrict__ r2,
    int M, int N, int K)
{
  int tiles_n = N >> 7;
  int bm = blockIdx.x / tiles_n, bn = blockIdx.x % tiles_n;
  int tid = threadIdx.x, wv = tid >> 6, lane = tid & 63, quad = lane >> 4, lc = lane & 15;
  int wm = wv & 1, wn = wv >> 1;

  // A tile 128x64 bf16 (16KB) + B tile 128x64 bf16 (16KB), XOR-swizzled 16B chunks
  __shared__ __align__(16) u16 lds_[16384];
  char* la = (char*)lds_;
  char* lb = (char*)lds_ + 16384;

  v4f acc[4][4] = {};

  for (int kt = 0; kt < K; kt += 64) {
    __syncthreads();
    #pragma unroll
    for (int c0 = 0; c0 < 4; ++c0) {
      int chunk = wv*4 + c0;                 // wave-uniform, 0..15
      int off = chunk*1024 + lane*16;        // byte offset within 16KB tile
      int row = off >> 7;                    // 128B per row
      int sc  = (off >> 4) & 7;              // stored 16B-chunk idx
      int lg  = sc ^ (row & 7);              // logical chunk (swizzle)
      const u16* ga = A  + (size_t)(bm*128 + row) * K + kt + lg*8;
      GLL16(ga, la + chunk*1024);
      const u16* gb = Bt + (size_t)(bn*128 + row) * K + kt + lg*8;
      GLL16(gb, lb + chunk*1024);
    }
    __syncthreads();   // implicit vmcnt(0) drain makes staged data visible

    #pragma unroll
    for (int kc = 0; kc < 2; ++kc) {
      v8bf af[4], bfr[4];
      #pragma unroll
      for (int r = 0; r < 4; ++r) {
        int row = wm*64 + r*16 + lc;
        int sc = (kc*4 + quad) ^ (row & 7);
        af[r] = *(const v8bf*)(la + row*128 + sc*16);
      }
      #pragma unroll
      for (int c = 0; c < 4; ++c) {
        int row = wn*64 + c*16 + lc;
        int sc = (kc*4 + quad) ^ (row & 7);
        bfr[c] = *(const v8bf*)(lb + row*128 + sc*16);
      }
      #pragma unroll
      for (int r = 0; r < 4; ++r)
        #pragma unroll
        for (int c = 0; c < 4; ++c)
          acc[r][c] = __builtin_amdgcn_mfma_f32_16x16x32_bf16(af[r], bfr[c], acc[r][c], 0, 0, 0);
    }
  }

  // epilogue; C/D layout: col = lane&15, row = quad*4 + reg
  #pragma unroll
  for (int r = 0; r < 4; ++r) {
    int grow = bm*128 + wm*64 + r*16 + quad*4;
    #pragma unroll
    for (int c = 0; c < 4; ++c) {
      int gcol = bn*128 + wn*64 + c*16 + lc;
      float bv = (EPI != 0) ? bias[gcol] : 0.f;
      #pragma unroll
      for (int i = 0; i < 4; ++i) {
        size_t idx = (size_t)(grow + i) * N + gcol;
        float v = acc[r][c][i] + bv;
        if (EPI == 0) {
          ((u16*)Cout)[idx] = f2bf(v);
        } else if (EPI == 1) {
          float ge = 0.5f * v * (1.f + erff(v * 0.70710678118654752f));
          ((u16*)Cout)[idx] = f2bf(ge);
        } else if (EPI == 2) {
          ((float*)Cout)[idx] = v;
        } else if (EPI == 3) {
          ((float*)Cout)[idx] = v + r1[idx] + r2[idx];
        } else {
          ((float*)Cout)[idx] = v + r1[idx];
        }
      }
    }
  }
}

// ---------------- Flash attention: Q,K,V bf16 (B,N,H*d) -> O bf16 ----------------
// grid: b*256 + h*16 + qt  (B=8, H=16, 16 q-tiles of 64 rows). 4 waves x 16 q-rows.
__global__ __launch_bounds__(256, 2) void attn_kernel(
    const u16* __restrict__ Q, const u16* __restrict__ K, const u16* __restrict__ V,
    u16* __restrict__ O)
{
  int bid = blockIdx.x;
  int qt = bid & 15, h = (bid >> 4) & 15, b = bid >> 8;
  int tid = threadIdx.x, wv = tid >> 6, lane = tid & 63, quad = lane >> 4, lc = lane & 15;

  __shared__ __align__(16) u16 sm_vt[64 * 136];       // V^T tile: d x kv, pad 128->136
  __shared__ __align__(16) u16 sm_p[4 * 16 * 136];    // per-wave P: 16 x kv, pad
  u16* Pw = sm_p + wv * 16 * 136;

  const float scale = 0.125f;   // d^-0.5, d=64

  // Q fragments (A-layout: m=lane&15, k=quad*8+j), held all kernel
  v8bf qf[2];
  {
    int qrow = qt*64 + wv*16 + lc;
    const u16* qp = Q + ((size_t)(b*1024 + qrow) * 1024 + h*64 + quad*8);
    qf[0] = *(const v8bf*)qp;
    qf[1] = *(const v8bf*)(qp + 32);
  }

  float m_i[4], l_i[4];
  v4f oacc[4] = {};
  #pragma unroll
  for (int i = 0; i < 4; ++i) { m_i[i] = -1e30f; l_i[i] = 0.f; }

  for (int it = 0; it < 8; ++it) {
    int kvb = it * 128;
    __syncthreads();   // protect previous iteration's LDS reads
    // stage V transposed: sm_vt[d][kv]
    #pragma unroll
    for (int p = 0; p < 4; ++p) {
      int t = tid + p*256;
      int kvr = t >> 3, ch = t & 7;
      const u16* vp = V + ((size_t)(b*1024 + kvb + kvr) * 1024 + h*64 + ch*8);
      uint4 tv = *(const uint4*)vp;
      const u16* tp = (const u16*)&tv;
      #pragma unroll
      for (int j = 0; j < 8; ++j)
        sm_vt[(ch*8 + j) * 136 + kvr] = tp[j];
    }
    __syncthreads();

    // S = Q K^T (C-layout: col=kv local, row=q local)
    v4f s[8] = {};
    #pragma unroll
    for (int ct = 0; ct < 8; ++ct) {
      int krow = kvb + ct*16 + lc;
      const u16* kp = K + ((size_t)(b*1024 + krow) * 1024 + h*64 + quad*8);
      v8bf kf0 = *(const v8bf*)kp;
      v8bf kf1 = *(const v8bf*)(kp + 32);
      s[ct] = __builtin_amdgcn_mfma_f32_16x16x32_bf16(qf[0], kf0, s[ct], 0, 0, 0);
      s[ct] = __builtin_amdgcn_mfma_f32_16x16x32_bf16(qf[1], kf1, s[ct], 0, 0, 0);
    }

    // online softmax in registers; rows of a 16x16 tile live in 16-lane groups (same quad)
    #pragma unroll
    for (int i = 0; i < 4; ++i) {
      float mx = m_i[i];
      #pragma unroll
      for (int ct = 0; ct < 8; ++ct) mx = fmaxf(mx, s[ct][i] * scale);
      mx = fmaxf(mx, __shfl_xor(mx, 1));
      mx = fmaxf(mx, __shfl_xor(mx, 2));
      mx = fmaxf(mx, __shfl_xor(mx, 4));
      mx = fmaxf(mx, __shfl_xor(mx, 8));
      float alpha = __expf(m_i[i] - mx);
      float rs = 0.f;
      #pragma unroll
      for (int ct = 0; ct < 8; ++ct) {
        float p = __expf(s[ct][i] * scale - mx);
        s[ct][i] = p;
        rs += p;
      }
      rs += __shfl_xor(rs, 1);
      rs += __shfl_xor(rs, 2);
      rs += __shfl_xor(rs, 4);
      rs += __shfl_xor(rs, 8);
      l_i[i] = l_i[i] * alpha + rs;
      m_i[i] = mx;
      #pragma unroll
      for (int t = 0; t < 4; ++t) oacc[t][i] *= alpha;
    }

    // P: C-layout regs -> LDS (then re-read in A-layout)
    #pragma unroll
    for (int ct = 0; ct < 8; ++ct)
      #pragma unroll
      for (int i = 0; i < 4; ++i)
        Pw[(quad*4 + i) * 136 + ct*16 + lc] = f2bf(s[ct][i]);
    __syncthreads();

    // O += P @ V
    #pragma unroll
    for (int k2 = 0; k2 < 4; ++k2) {
      v8bf pf = *(const v8bf*)(Pw + lc*136 + k2*32 + quad*8);
      #pragma unroll
      for (int vt = 0; vt < 4; ++vt) {
        v8bf vf = *(const v8bf*)(sm_vt + (vt*16 + lc)*136 + k2*32 + quad*8);
        oacc[vt] = __builtin_amdgcn_mfma_f32_16x16x32_bf16(pf, vf, oacc[vt], 0, 0, 0);
      }
    }
  }

  // normalize + store
  #pragma unroll
  for (int i = 0; i < 4; ++i) {
    float inv = 1.f / l_i[i];
    int row = qt*64 + wv*16 + quad*4 + i;
    #pragma unroll
    for (int vt = 0; vt < 4; ++vt) {
      int col = h*64 + vt*16 + lc;
      O[(size_t)(b*1024 + row) * 1024 + col] = f2bf(oacc[vt][i] * inv);
    }
  }
}

// ---------------- host ----------------
extern "C" void kernel_launch(void* const* d_in, const int* in_sizes, int n_in,
                              void* d_out, int out_size, void* d_ws, size_t ws_size,
                              hipStream_t stream)
{
  const float* x1    = (const float*)d_in[0];
  const float* x2    = (const float*)d_in[1];
  const float* x3    = (const float*)d_in[2];
  const float* ln11g = (const float*)d_in[3];
  const float* ln11b = (const float*)d_in[4];
  const float* ln12g = (const float*)d_in[5];
  const float* ln12b = (const float*)d_in[6];
  const float* ln21g = (const float*)d_in[7];
  const float* ln21b = (const float*)d_in[8];
  const float* ln23g = (const float*)d_in[9];
  const float* ln23b = (const float*)d_in[10];
  const float* ln2g  = (const float*)d_in[11];
  const float* ln2b  = (const float*)d_in[12];
  const float* a1wq  = (const float*)d_in[13];
  const float* a1wk  = (const float*)d_in[14];
  const float* a1wv  = (const float*)d_in[15];
  const float* a1wp  = (const float*)d_in[16];
  const float* a1bp  = (const float*)d_in[17];
  const float* a2wq  = (const float*)d_in[18];
  const float* a2wk  = (const float*)d_in[19];
  const float* a2wv  = (const float*)d_in[20];
  const float* a2wp  = (const float*)d_in[21];
  const float* a2bp  = (const float*)d_in[22];
  const float* fc1w  = (const float*)d_in[23];
  const float* fc1b  = (const float*)d_in[24];
  const float* fc2w  = (const float*)d_in[25];
  const float* fc2b  = (const float*)d_in[26];

  const int M = 8192, C = 1024, HID = 4096;
  char* ws = (char*)d_ws;
  u16* WT = (u16*)ws;                                   // 8 MB weight scratch
  #define SLOT(i) ((void*)(ws + ((size_t)8 << 20) + (size_t)(i) * ((size_t)16 << 20)))

  dim3 blk(256);
  const int gC  = (M/128) * (C/128);     // 512 blocks
  const int gH  = (M/128) * (HID/128);   // 2048 blocks
  const int tCC = (C/32) * (C/32);       // 1024

  // ---- branch 1 ----
  ln_kernel<<<M, blk, 0, stream>>>(x1, ln11g, ln11b, (u16*)SLOT(0));      // xq1
  ln_kernel<<<M, blk, 0, stream>>>(x2, ln12g, ln12b, (u16*)SLOT(1));      // xkv1

  transpose_cast<<<tCC, blk, 0, stream>>>(a1wq, WT, C, C);
  gemm_bf16<0><<<gC, blk, 0, stream>>>((u16*)SLOT(0), WT, SLOT(2), nullptr, nullptr, nullptr, M, C, C);   // Q1
  transpose_cast<<<tCC, blk, 0, stream>>>(a1wk, WT, C, C);
  gemm_bf16<0><<<gC, blk, 0, stream>>>((u16*)SLOT(1), WT, SLOT(3), nullptr, nullptr, nullptr, M, C, C);   // K1
  transpose_cast<<<tCC, blk, 0, stream>>>(a1wv, WT, C, C);
  gemm_bf16<0><<<gC, blk, 0, stream>>>((u16*)SLOT(1), WT, SLOT(4), nullptr, nullptr, nullptr, M, C, C);   // V1

  attn_kernel<<<2048, blk, 0, stream>>>((u16*)SLOT(2), (u16*)SLOT(3), (u16*)SLOT(4), (u16*)SLOT(0));      // O1

  transpose_cast<<<tCC, blk, 0, stream>>>(a1wp, WT, C, C);
  gemm_bf16<2><<<gC, blk, 0, stream>>>((u16*)SLOT(0), WT, SLOT(5), a1bp, nullptr, nullptr, M, C, C);      // o1 fp32 (S5+S6)

  // ---- branch 2 ----
  ln_kernel<<<M, blk, 0, stream>>>(x1, ln21g, ln21b, (u16*)SLOT(1));      // xq2
  ln_kernel<<<M, blk, 0, stream>>>(x3, ln23g, ln23b, (u16*)SLOT(2));      // xkv2

  transpose_cast<<<tCC, blk, 0, stream>>>(a2wq, WT, C, C);
  gemm_bf16<0><<<gC, blk, 0, stream>>>((u16*)SLOT(1), WT, SLOT(3), nullptr, nullptr, nullptr, M, C, C);   // Q2
  transpose_cast<<<tCC, blk, 0, stream>>>(a2wk, WT, C, C);
  gemm_bf16<0><<<gC, blk, 0, stream>>>((u16*)SLOT(2), WT, SLOT(4), nullptr, nullptr, nullptr, M, C, C);   // K2
  transpose_cast<<<tCC, blk, 0, stream>>>(a2wv, WT, C, C);
  gemm_bf16<0><<<gC, blk, 0, stream>>>((u16*)SLOT(2), WT, SLOT(0), nullptr, nullptr, nullptr, M, C, C);   // V2

  attn_kernel<<<2048, blk, 0, stream>>>((u16*)SLOT(3), (u16*)SLOT(4), (u16*)SLOT(0), (u16*)SLOT(1));      // O2

  transpose_cast<<<tCC, blk, 0, stream>>>(a2wp, WT, C, C);
  // x = x1 + o1 + (O2 @ wp2 + bp2), fp32 into S2+S3
  gemm_bf16<3><<<gC, blk, 0, stream>>>((u16*)SLOT(1), WT, SLOT(2), a2bp, x1, (const float*)SLOT(5), M, C, C);

  // ---- MLP ----
  ln_kernel<<<M, blk, 0, stream>>>((const float*)SLOT(2), ln2g, ln2b, (u16*)SLOT(4));                     // xln
  transpose_cast<<<(C/32)*(HID/32), blk, 0, stream>>>(fc1w, WT, C, HID);
  gemm_bf16<1><<<gH, blk, 0, stream>>>((u16*)SLOT(4), WT, SLOT(5), fc1b, nullptr, nullptr, M, HID, C);    // h bf16 (S5..S8)
  transpose_cast<<<(HID/32)*(C/32), blk, 0, stream>>>(fc2w, WT, HID, C);
  gemm_bf16<4><<<gC, blk, 0, stream>>>((u16*)SLOT(5), WT, d_out, fc2b, (const float*)SLOT(2), nullptr, M, C, HID);
  #undef SLOT
}

// Round 2
// 772.113 us; speedup vs baseline: 1.2347x; 1.2347x over previous
//
#include <hip/hip_runtime.h>
#include <hip/hip_bf16.h>
#include <cstdint>

typedef unsigned short u16;
typedef __bf16 v8bf __attribute__((ext_vector_type(8)));
typedef short v4s __attribute__((ext_vector_type(4)));
typedef float v4f __attribute__((ext_vector_type(4)));

__device__ __forceinline__ u16 f2bf(float f) {
  union { float f; uint32_t u; } v; v.f = f;
  return (u16)((v.u + 0x7fffu + ((v.u >> 16) & 1u)) >> 16);
}

// async global->LDS, 16B per lane; LDS dest = wave-uniform base + lane*16
#define GLL16(gsrc, ldst) \
  __builtin_amdgcn_global_load_lds((__attribute__((address_space(1))) void*)(gsrc), \
      (__attribute__((address_space(3))) void*)(ldst), 16, 0, 0)

// ---------------- LayerNorm: fp32 row -> bf16 row ----------------
__global__ __launch_bounds__(256) void ln_kernel(
    const float* __restrict__ x, const float* __restrict__ g, const float* __restrict__ bt,
    u16* __restrict__ out)
{
  int row = blockIdx.x, tid = threadIdx.x;
  const float4* xr = (const float4*)(x + (size_t)row * 1024);
  float4 v = xr[tid];
  float s = v.x + v.y + v.z + v.w;
  float ss = v.x*v.x + v.y*v.y + v.z*v.z + v.w*v.w;
  for (int d = 1; d < 64; d <<= 1) { s += __shfl_xor(s, d); ss += __shfl_xor(ss, d); }
  __shared__ float red[8];
  int wv = tid >> 6, lane = tid & 63;
  if (lane == 0) { red[wv] = s; red[4 + wv] = ss; }
  __syncthreads();
  s  = red[0] + red[1] + red[2] + red[3];
  ss = red[4] + red[5] + red[6] + red[7];
  float mean = s * (1.f/1024.f);
  float var  = ss * (1.f/1024.f) - mean*mean;      // biased var == jnp.var
  float rs = rsqrtf(var + 1e-5f);
  float4 gv = ((const float4*)g)[tid];
  float4 bv = ((const float4*)bt)[tid];
  ushort4 o;
  o.x = f2bf((v.x-mean)*rs*gv.x + bv.x);
  o.y = f2bf((v.y-mean)*rs*gv.y + bv.y);
  o.z = f2bf((v.z-mean)*rs*gv.z + bv.z);
  o.w = f2bf((v.w-mean)*rs*gv.w + bv.w);
  ((ushort4*)out)[(size_t)row*256 + tid] = o;
}

// ------------- Weight transpose + fp32->bf16 cast: W[K][N] -> WT[N][K] -------------
__global__ __launch_bounds__(256) void transpose_cast(
    const float* __restrict__ W, u16* __restrict__ WT, int K, int N)
{
  __shared__ float t[32][33];
  int tiles_n = N >> 5;
  int bn = blockIdx.x % tiles_n, bk = blockIdx.x / tiles_n;
  int tx = threadIdx.x & 31, ty = threadIdx.x >> 5;   // 32 x 8
  #pragma unroll
  for (int j = 0; j < 4; ++j)
    t[ty + j*8][tx] = W[(size_t)(bk*32 + ty + j*8) * N + bn*32 + tx];
  __syncthreads();
  #pragma unroll
  for (int j = 0; j < 4; ++j)
    WT[(size_t)(bn*32 + ty + j*8) * K + bk*32 + tx] = f2bf(t[tx][ty + j*8]);
}

// ---------------- GEMM: C[M,N] = A[M,K](bf16) * Wt[N,K](bf16)^T, templated epilogue ----------------
// EPI: 0 = bf16 out; 1 = bias+GELU(exact) bf16 out; 2 = bias fp32 out;
//      3 = bias + r1 + r2 fp32 out; 4 = bias + r1 fp32 out; 5 = bf16 TRANSPOSED out (Ct[N][M])
template<int EPI>
__global__ __launch_bounds__(256, 2) void gemm_bf16(
    const u16* __restrict__ A, const u16* __restrict__ Bt, void* __restrict__ Cout,
    const float* __restrict__ bias, const float* __restrict__ r1, const float* __restrict__ r2,
    int M, int N, int K)
{
  int tiles_n = N >> 7;
  int bm = blockIdx.x / tiles_n, bn = blockIdx.x % tiles_n;
  int tid = threadIdx.x, wv = tid >> 6, lane = tid & 63, quad = lane >> 4, lc = lane & 15;
  int wm = wv & 1, wn = wv >> 1;

  __shared__ __align__(16) u16 lds_[16384];
  char* la = (char*)lds_;
  char* lb = (char*)lds_ + 16384;

  v4f acc[4][4] = {};

  for (int kt = 0; kt < K; kt += 64) {
    __syncthreads();
    #pragma unroll
    for (int c0 = 0; c0 < 4; ++c0) {
      int chunk = wv*4 + c0;
      int off = chunk*1024 + lane*16;
      int row = off >> 7;
      int sc  = (off >> 4) & 7;
      int lg  = sc ^ (row & 7);
      const u16* ga = A  + (size_t)(bm*128 + row) * K + kt + lg*8;
      GLL16(ga, la + chunk*1024);
      const u16* gb = Bt + (size_t)(bn*128 + row) * K + kt + lg*8;
      GLL16(gb, lb + chunk*1024);
    }
    __syncthreads();

    #pragma unroll
    for (int kc = 0; kc < 2; ++kc) {
      v8bf af[4], bfr[4];
      #pragma unroll
      for (int r = 0; r < 4; ++r) {
        int row = wm*64 + r*16 + lc;
        int sc = (kc*4 + quad) ^ (row & 7);
        af[r] = *(const v8bf*)(la + row*128 + sc*16);
      }
      #pragma unroll
      for (int c = 0; c < 4; ++c) {
        int row = wn*64 + c*16 + lc;
        int sc = (kc*4 + quad) ^ (row & 7);
        bfr[c] = *(const v8bf*)(lb + row*128 + sc*16);
      }
      #pragma unroll
      for (int r = 0; r < 4; ++r)
        #pragma unroll
        for (int c = 0; c < 4; ++c)
          acc[r][c] = __builtin_amdgcn_mfma_f32_16x16x32_bf16(af[r], bfr[c], acc[r][c], 0, 0, 0);
    }
  }

  // epilogue; C/D layout: col = lane&15, row = quad*4 + reg
  #pragma unroll
  for (int r = 0; r < 4; ++r) {
    int grow = bm*128 + wm*64 + r*16 + quad*4;
    #pragma unroll
    for (int c = 0; c < 4; ++c) {
      int gcol = bn*128 + wn*64 + c*16 + lc;
      if (EPI == 5) {
        ushort4 o;
        o.x = f2bf(acc[r][c][0]); o.y = f2bf(acc[r][c][1]);
        o.z = f2bf(acc[r][c][2]); o.w = f2bf(acc[r][c][3]);
        *(ushort4*)((u16*)Cout + (size_t)gcol * M + grow) = o;
        continue;
      }
      float bv = (EPI != 0) ? bias[gcol] : 0.f;
      #pragma unroll
      for (int i = 0; i < 4; ++i) {
        size_t idx = (size_t)(grow + i) * N + gcol;
        float v = acc[r][c][i] + bv;
        if (EPI == 0) {
          ((u16*)Cout)[idx] = f2bf(v);
        } else if (EPI == 1) {
          float ge = 0.5f * v * (1.f + erff(v * 0.70710678118654752f));
          ((u16*)Cout)[idx] = f2bf(ge);
        } else if (EPI == 2) {
          ((float*)Cout)[idx] = v;
        } else if (EPI == 3) {
          ((float*)Cout)[idx] = v + r1[idx] + r2[idx];
        } else {
          ((float*)Cout)[idx] = v + r1[idx];
        }
      }
    }
  }
}

// ---------------- Flash attention, transposed-S formulation ----------------
// Q,K: bf16 [token][1024]; VT: bf16 [1024][8192] (channel-major); O: bf16 [token][1024]
// grid: b*256 + h*16 + qt. 4 waves; wave wv owns q-cols qt*64+wv*16+lc.
__global__ __launch_bounds__(256, 2) void attn_kernel(
    const u16* __restrict__ Q, const u16* __restrict__ K, const u16* __restrict__ VT,
    u16* __restrict__ O)
{
  int bid = blockIdx.x;
  int qt = bid & 15, h = (bid >> 4) & 15, b = bid >> 8;
  int tid = threadIdx.x, wv = tid >> 6, lane = tid & 63, quad = lane >> 4, lc = lane & 15;

  __shared__ __align__(16) char lds_[32768];
  char* kt_l = lds_;            // K tile [128 kv][64 d], 128B rows, chunk^(row&7) swizzle
  char* vt_l = lds_ + 16384;    // VT tile [64 d][128 kv], 256B rows, chunk^(row&15) swizzle

  const float scale = 0.125f;   // d^-0.5

  // Q fragments, B-operand of S^T = K * Q^T (lane lc = q col, k = quad*8+j)
  v8bf qf[2];
  {
    int qrow = qt*64 + wv*16 + lc;
    const u16* qp = Q + ((size_t)(b*1024 + qrow) * 1024 + h*64 + quad*8);
    qf[0] = *(const v8bf*)qp;
    qf[1] = *(const v8bf*)(qp + 32);
  }

  float m_i = -1e30f, l_i = 0.f;
  v4f oacc[4] = {};   // O^T: d = dt*16 + quad*4 + i, q = lc

  for (int it = 0; it < 8; ++it) {
    int kvb = it * 128;
    __syncthreads();
    // stage K tile: 16 chunks of 1KB; wave wv does chunks wv*4..wv*4+3
    #pragma unroll
    for (int c0 = 0; c0 < 4; ++c0) {
      int ch = wv*4 + c0;
      int off = ch*1024 + lane*16;
      { // K
        int row = off >> 7, sc = (off >> 4) & 7, lg = sc ^ (row & 7);
        const u16* g = K + (size_t)(b*1024 + kvb + row) * 1024 + h*64 + lg*8;
        GLL16(g, kt_l + ch*1024);
      }
      { // VT
        int row = off >> 8, sc = (off >> 4) & 15, lg = sc ^ (row & 15);
        const u16* g = VT + (size_t)(h*64 + row) * 8192 + b*1024 + kvb + lg*8;
        GLL16(g, vt_l + ch*1024);
      }
    }
    __syncthreads();   // barrier drains vmcnt -> staged data visible

    // S^T = K * Q^T : C-layout col = q (lc), row = kv = ct*16 + quad*4 + i
    v4f s[8] = {};
    #pragma unroll
    for (int ct = 0; ct < 8; ++ct) {
      int row = ct*16 + lc;
      #pragma unroll
      for (int kc = 0; kc < 2; ++kc) {
        int sc = (kc*4 + quad) ^ (row & 7);
        v8bf kf = *(const v8bf*)(kt_l + row*128 + sc*16);
        s[ct] = __builtin_amdgcn_mfma_f32_16x16x32_bf16(kf, qf[kc], s[ct], 0, 0, 0);
      }
    }

    // online softmax over kv (regs + quads); each lane owns one q (replicated x4)
    float mx = m_i;
    #pragma unroll
    for (int ct = 0; ct < 8; ++ct)
      #pragma unroll
      for (int i = 0; i < 4; ++i) mx = fmaxf(mx, s[ct][i] * scale);
    mx = fmaxf(mx, __shfl_xor(mx, 16));
    mx = fmaxf(mx, __shfl_xor(mx, 32));
    float alpha = __expf(m_i - mx);
    float rs = 0.f;
    #pragma unroll
    for (int ct = 0; ct < 8; ++ct)
      #pragma unroll
      for (int i = 0; i < 4; ++i) {
        float p = __expf(s[ct][i] * scale - mx);
        s[ct][i] = p;
        rs += p;
      }
    rs += __shfl_xor(rs, 16);
    rs += __shfl_xor(rs, 32);
    l_i = l_i * alpha + rs;
    m_i = mx;
    #pragma unroll
    for (int dt = 0; dt < 4; ++dt)
      #pragma unroll
      for (int i = 0; i < 4; ++i) oacc[dt][i] *= alpha;

    // O^T += V^T * P^T via 16x16x16 mfma: P^T B-frag comes straight from s[] regs
    #pragma unroll
    for (int ct = 0; ct < 8; ++ct) {
      v4s pfrag;
      #pragma unroll
      for (int i = 0; i < 4; ++i) pfrag[i] = (short)f2bf(s[ct][i]);
      int lg = ct*2 + (quad >> 1);
      int ho = (quad & 1) * 8;
      #pragma unroll
      for (int dt = 0; dt < 4; ++dt) {
        int rowd = dt*16 + lc;
        int sc = lg ^ (rowd & 15);
        v4s vfrag = *(const v4s*)(vt_l + rowd*256 + sc*16 + ho);
        oacc[dt] = __builtin_amdgcn_mfma_f32_16x16x16bf16_1k(vfrag, pfrag, oacc[dt], 0, 0, 0);
      }
    }
  }

  // transpose O^T -> O through swizzled LDS (per-wave 16q x 64d region in kt_l)
  __syncthreads();   // everyone done reading kt_l/vt_l
  {
    char* base = kt_l + wv*2048;   // rows = q (128B each, 8 chunks, chunk^(q&7))
    float inv = 1.f / l_i;
    #pragma unroll
    for (int dt = 0; dt < 4; ++dt) {
      ushort4 o;
      o.x = f2bf(oacc[dt][0]*inv); o.y = f2bf(oacc[dt][1]*inv);
      o.z = f2bf(oacc[dt][2]*inv); o.w = f2bf(oacc[dt][3]*inv);
      int lg = dt*2 + (quad >> 1);
      int sc = lg ^ (lc & 7);
      *(ushort4*)(base + lc*128 + sc*16 + (quad & 1)*8) = o;
    }
  }
  __syncthreads();
  {
    char* base = kt_l + wv*2048;
    #pragma unroll
    for (int rep = 0; rep < 2; ++rep) {
      int qr = rep*8 + (lane >> 3);
      int ch = lane & 7;
      int sc = ch ^ (qr & 7);
      uint4 d = *(const uint4*)(base + qr*128 + sc*16);
      *(uint4*)(O + (size_t)(b*1024 + qt*64 + wv*16 + qr) * 1024 + h*64 + ch*8) = d;
    }
  }
}

// ---------------- host ----------------
extern "C" void kernel_launch(void* const* d_in, const int* in_sizes, int n_in,
                              void* d_out, int out_size, void* d_ws, size_t ws_size,
                              hipStream_t stream)
{
  const float* x1    = (const float*)d_in[0];
  const float* x2    = (const float*)d_in[1];
  const float* x3    = (const float*)d_in[2];
  const float* ln11g = (const float*)d_in[3];
  const float* ln11b = (const float*)d_in[4];
  const float* ln12g = (const float*)d_in[5];
  const float* ln12b = (const float*)d_in[6];
  const float* ln21g = (const float*)d_in[7];
  const float* ln21b = (const float*)d_in[8];
  const float* ln23g = (const float*)d_in[9];
  const float* ln23b = (const float*)d_in[10];
  const float* ln2g  = (const float*)d_in[11];
  const float* ln2b  = (const float*)d_in[12];
  const float* a1wq  = (const float*)d_in[13];
  const float* a1wk  = (const float*)d_in[14];
  const float* a1wv  = (const float*)d_in[15];
  const float* a1wp  = (const float*)d_in[16];
  const float* a1bp  = (const float*)d_in[17];
  const float* a2wq  = (const float*)d_in[18];
  const float* a2wk  = (const float*)d_in[19];
  const float* a2wv  = (const float*)d_in[20];
  const float* a2wp  = (const float*)d_in[21];
  const float* a2bp  = (const float*)d_in[22];
  const float* fc1w  = (const float*)d_in[23];
  const float* fc1b  = (const float*)d_in[24];
  const float* fc2w  = (const float*)d_in[25];
  const float* fc2b  = (const float*)d_in[26];

  const int M = 8192, C = 1024, HID = 4096;
  char* ws = (char*)d_ws;
  u16* WT = (u16*)ws;                                   // 8 MB weight scratch
  #define SLOT(i) ((void*)(ws + ((size_t)8 << 20) + (size_t)(i) * ((size_t)16 << 20)))

  dim3 blk(256);
  const int gC  = (M/128) * (C/128);     // 512
  const int gH  = (M/128) * (HID/128);   // 2048
  const int tCC = (C/32) * (C/32);       // 1024

  // ---- branch 1 ----
  ln_kernel<<<M, blk, 0, stream>>>(x1, ln11g, ln11b, (u16*)SLOT(0));      // xq1
  ln_kernel<<<M, blk, 0, stream>>>(x2, ln12g, ln12b, (u16*)SLOT(1));      // xkv1

  transpose_cast<<<tCC, blk, 0, stream>>>(a1wq, WT, C, C);
  gemm_bf16<0><<<gC, blk, 0, stream>>>((u16*)SLOT(0), WT, SLOT(2), nullptr, nullptr, nullptr, M, C, C);   // Q1
  transpose_cast<<<tCC, blk, 0, stream>>>(a1wk, WT, C, C);
  gemm_bf16<0><<<gC, blk, 0, stream>>>((u16*)SLOT(1), WT, SLOT(3), nullptr, nullptr, nullptr, M, C, C);   // K1
  transpose_cast<<<tCC, blk, 0, stream>>>(a1wv, WT, C, C);
  gemm_bf16<5><<<gC, blk, 0, stream>>>((u16*)SLOT(1), WT, SLOT(4), nullptr, nullptr, nullptr, M, C, C);   // VT1

  attn_kernel<<<2048, blk, 0, stream>>>((u16*)SLOT(2), (u16*)SLOT(3), (u16*)SLOT(4), (u16*)SLOT(0));      // O1

  transpose_cast<<<tCC, blk, 0, stream>>>(a1wp, WT, C, C);
  gemm_bf16<2><<<gC, blk, 0, stream>>>((u16*)SLOT(0), WT, SLOT(5), a1bp, nullptr, nullptr, M, C, C);      // o1 fp32 (S5+S6)

  // ---- branch 2 ----
  ln_kernel<<<M, blk, 0, stream>>>(x1, ln21g, ln21b, (u16*)SLOT(1));      // xq2
  ln_kernel<<<M, blk, 0, stream>>>(x3, ln23g, ln23b, (u16*)SLOT(2));      // xkv2

  transpose_cast<<<tCC, blk, 0, stream>>>(a2wq, WT, C, C);
  gemm_bf16<0><<<gC, blk, 0, stream>>>((u16*)SLOT(1), WT, SLOT(3), nullptr, nullptr, nullptr, M, C, C);   // Q2
  transpose_cast<<<tCC, blk, 0, stream>>>(a2wk, WT, C, C);
  gemm_bf16<0><<<gC, blk, 0, stream>>>((u16*)SLOT(2), WT, SLOT(4), nullptr, nullptr, nullptr, M, C, C);   // K2
  transpose_cast<<<tCC, blk, 0, stream>>>(a2wv, WT, C, C);
  gemm_bf16<5><<<gC, blk, 0, stream>>>((u16*)SLOT(2), WT, SLOT(0), nullptr, nullptr, nullptr, M, C, C);   // VT2

  attn_kernel<<<2048, blk, 0, stream>>>((u16*)SLOT(3), (u16*)SLOT(4), (u16*)SLOT(0), (u16*)SLOT(1));      // O2

  transpose_cast<<<tCC, blk, 0, stream>>>(a2wp, WT, C, C);
  gemm_bf16<3><<<gC, blk, 0, stream>>>((u16*)SLOT(1), WT, SLOT(2), a2bp, x1, (const float*)SLOT(5), M, C, C);

  // ---- MLP ----
  ln_kernel<<<M, blk, 0, stream>>>((const float*)SLOT(2), ln2g, ln2b, (u16*)SLOT(4));                     // xln
  transpose_cast<<<(C/32)*(HID/32), blk, 0, stream>>>(fc1w, WT, C, HID);
  gemm_bf16<1><<<gH, blk, 0, stream>>>((u16*)SLOT(4), WT, SLOT(5), fc1b, nullptr, nullptr, M, HID, C);    // h bf16 (S5..S8)
  transpose_cast<<<(HID/32)*(C/32), blk, 0, stream>>>(fc2w, WT, HID, C);
  gemm_bf16<4><<<gC, blk, 0, stream>>>((u16*)SLOT(5), WT, d_out, fc2b, (const float*)SLOT(2), nullptr, M, C, HID);
  #undef SLOT
}